// Round 10
// baseline (249.229 us; speedup 1.0000x reference)
//
#include <hip/hip_runtime.h>
#include <hip/hip_bf16.h>

#define S_LEN 8192
#define NH 128
#define NM 16
#define NB 32
#define NBATCH 32
#define GP2 136         // k_fused Glds s-pitch (128 + 8)

typedef __hip_bfloat16 bf16;
typedef unsigned short ushort_t;
typedef unsigned int uint_t;

typedef __bf16 bf16x8 __attribute__((ext_vector_type(8)));
typedef float floatx4 __attribute__((ext_vector_type(4)));

__device__ __forceinline__ float b2f(bf16 v){ return __bfloat162float(v); }
__device__ __forceinline__ float ldf(const void* p, long i, int f32){
    return f32 ? ((const float*)p)[i] : b2f(((const bf16*)p)[i]);
}
// A&S 7.1.26 erf, |eps|<=1.5e-7
__device__ __forceinline__ float gelu_fast(float x){
    float z = fabsf(x) * 0.70710678118654752440f;
    float t = __builtin_amdgcn_rcpf(__builtin_fmaf(0.3275911f, z, 1.0f));
    float p = t*(0.254829592f + t*(-0.284496736f + t*(1.421413741f +
              t*(-1.453152027f + t*1.061405429f))));
    float e = __expf(-z * z);
    float er = __builtin_fmaf(-p, e, 1.0f);
    float s = copysignf(er, x);
    return 0.5f * x * (1.0f + s);
}
__device__ __forceinline__ ushort_t f2us(float v){
    return __builtin_bit_cast(ushort_t, (__bf16)v);
}
__device__ __forceinline__ void split_bf(float v, ushort_t& hi, ushort_t& lo){
    __bf16 h = (__bf16)v;
    float r = v - (float)h;
    hi = __builtin_bit_cast(ushort_t, h);
    lo = __builtin_bit_cast(ushort_t, (__bf16)r);
}
__device__ __forceinline__ bf16x8 ld8(const ushort_t* p){
    return *(const bf16x8*)(const void*)p;
}
__device__ __forceinline__ floatx4 MF(bf16x8 a, bf16x8 b, floatx4 c){
    return __builtin_amdgcn_mfma_f32_16x16x32_bf16(a, b, c, 0, 0, 0);
}

// wave-0 dtype sniff (first 8 KB of x), broadcast via LDS. prep-only.
__device__ __forceinline__ int detect_f32(const void* x, int tid){
    __shared__ int sflag;
    if (tid < 64){
        const ushort_t* p = (const ushort_t*)x;
        int cnt = 0;
        for (int i = tid; i < 4096; i += 64){
            int e = (p[i] >> 7) & 0xFF;
            if (e >= 0xA0) cnt++;
        }
        #pragma unroll
        for (int off = 32; off > 0; off >>= 1) cnt += __shfl_xor(cnt, off, 64);
        if (tid == 0) sflag = (cnt > 400) ? 1 : 0;
    }
    __syncthreads();
    return sflag;
}

// ---- k_prep: blocks 0..511 modal DFT of x -> M (vectorized x loads);
//      512..1023 basis tables + zero C0; block 512 caches dtype flag.
__global__ __launch_bounds__(256) void k_prep(const void* __restrict__ x,
                                              const void* __restrict__ pw,
                                              const void* __restrict__ pb,
                                              float* __restrict__ M,
                                              ushort_t* __restrict__ Thi,
                                              ushort_t* __restrict__ Tlo,
                                              ushort_t* __restrict__ TThi,
                                              float* __restrict__ C0,
                                              uint_t* __restrict__ flag){
    int bid = blockIdx.x;
    int tid = threadIdx.x;
    int f32 = detect_f32(x, tid);
    if (bid < 512){
        int m = bid >> 5, b = bid & 31;
        float re = 0.f, im = 0.f;
        #pragma unroll
        for (int g = 0; g < 4; g++){
            int s0 = g * 2048 + tid * 8;
            float xv[8];
            if (f32){
                const float4* xp = (const float4*)((const float*)x
                                    + (long)b * S_LEN + s0);
                float4 v0 = xp[0], v1 = xp[1];
                xv[0]=v0.x; xv[1]=v0.y; xv[2]=v0.z; xv[3]=v0.w;
                xv[4]=v1.x; xv[5]=v1.y; xv[6]=v1.z; xv[7]=v1.w;
            } else {
                bf16x8 v = ld8((const ushort_t*)x + (long)b * S_LEN + s0);
                #pragma unroll
                for (int e = 0; e < 8; e++) xv[e] = (float)v[e];
            }
            if (m){
                #pragma unroll
                for (int e = 0; e < 8; e++){
                    int r = (m * (s0 + e)) & (S_LEN - 1);
                    float rev = (float)r * (1.0f / (float)S_LEN);
                    re += xv[e] * __builtin_amdgcn_cosf(rev);
                    im -= xv[e] * __builtin_amdgcn_sinf(rev);
                }
            } else {
                #pragma unroll
                for (int e = 0; e < 8; e++) re += xv[e];
            }
        }
        __shared__ float sred[8];
        #pragma unroll
        for (int off = 32; off > 0; off >>= 1){
            re += __shfl_xor(re, off, 64);
            im += __shfl_xor(im, off, 64);
        }
        int w = tid >> 6;
        if ((tid & 63) == 0){ sred[w] = re; sred[4 + w] = im; }
        __syncthreads();
        if (tid < NH){
            float Xre = sred[0] + sred[1] + sred[2] + sred[3];
            float Xim = sred[4] + sred[5] + sred[6] + sred[7];
            int h = tid;
            float pwv = ldf(pw, h, f32);
            float fc = pwv * Xre + (m == 0 ? (float)S_LEN * ldf(pb, h, f32) : 0.f);
            float fs = -pwv * Xim;
            float* Mb = M + (long)b * NB * NH;
            Mb[m * NH + h]        = fc;
            Mb[(NM + m) * NH + h] = fs;
        }
    } else {
        int bb = bid - 512;
        int s = bb * 16 + (tid >> 4);
        int m = tid & 15;
        float cv = 1.f, sv = 0.f;
        if (m){
            int r = (m * s) & (S_LEN - 1);
            float rev = (float)r * (1.0f / (float)S_LEN);
            sv = __builtin_amdgcn_sinf(rev);
            cv = __builtin_amdgcn_cosf(rev);
        }
        ushort_t chi, clo, shi, slo;
        split_bf(cv, chi, clo);
        split_bf(sv, shi, slo);
        Thi[s * NB + m] = chi;       Tlo[s * NB + m] = clo;
        Thi[s * NB + NM + m] = shi;  Tlo[s * NB + NM + m] = slo;
        TThi[m * S_LEN + s] = chi;
        TThi[(NM + m) * S_LEN + s] = shi;
        C0[bb * 256 + tid] = 0.f;    // zero layer-0 C buffer
        if (bb == 0 && tid == 0) flag[0] = (uint_t)f32;
    }
}

// ---- mixA: mode-split grid (8 hc, 2 mg, 32 b) = 512 blocks (2/CU).
//      Stage M[b] 16-h chunk -> 8-mode partial C -> atomic into C[b][j][k].
__global__ __launch_bounds__(256) void k_mixA(const uint_t* __restrict__ flag,
                                              const float* __restrict__ M,
                                              const void* __restrict__ wre,
                                              const void* __restrict__ wim,
                                              long woff,
                                              float* __restrict__ C){
    int tid = threadIdx.x;
    int f32 = (int)flag[0];
    int hc = blockIdx.x, mg = blockIdx.y, b = blockIdx.z;
    int k = tid & 127, msub = tid >> 7;
    int m0 = mg * 8 + msub * 4;     // 4 modes per thread
    int h0 = hc * 16;
    __shared__ float Ms[NB * 16];
    for (int i = tid; i < NB * 16; i += 256){
        int j = i >> 4, hh = i & 15;
        Ms[j * 16 + hh] = M[(long)b * NB * NH + j * NH + h0 + hh];
    }
    __syncthreads();
    float Cr[4] = {0,0,0,0}, Ci[4] = {0,0,0,0};
    #pragma unroll 8
    for (int hh = 0; hh < 16; hh++){
        long base = woff + ((long)(h0 + hh) * NH + k) * NM + m0;
        float wr[4], wi[4];
        if (f32){
            float4 a  = *(const float4*)((const float*)wre + base);
            float4 cc = *(const float4*)((const float*)wim + base);
            wr[0]=a.x;  wr[1]=a.y;  wr[2]=a.z;  wr[3]=a.w;
            wi[0]=cc.x; wi[1]=cc.y; wi[2]=cc.z; wi[3]=cc.w;
        } else {
            ushort4 a  = *(const ushort4*)((const ushort_t*)wre + base);
            ushort4 cc = *(const ushort4*)((const ushort_t*)wim + base);
            wr[0]=b2f(__builtin_bit_cast(bf16, a.x));
            wr[1]=b2f(__builtin_bit_cast(bf16, a.y));
            wr[2]=b2f(__builtin_bit_cast(bf16, a.z));
            wr[3]=b2f(__builtin_bit_cast(bf16, a.w));
            wi[0]=b2f(__builtin_bit_cast(bf16, cc.x));
            wi[1]=b2f(__builtin_bit_cast(bf16, cc.y));
            wi[2]=b2f(__builtin_bit_cast(bf16, cc.z));
            wi[3]=b2f(__builtin_bit_cast(bf16, cc.w));
        }
        #pragma unroll
        for (int e = 0; e < 4; e++){
            float fc = Ms[(m0 + e) * 16 + hh];
            float fs = Ms[(NM + m0 + e) * 16 + hh];
            Cr[e] += fc * wr[e] + fs * wi[e];
            Ci[e] += fc * wi[e] - fs * wr[e];
        }
    }
    float* Cb = C + (long)b * NB * NH;
    #pragma unroll
    for (int e = 0; e < 4; e++){
        atomicAdd(&Cb[(m0 + e) * NH + k],      Cr[e]);
        atomicAdd(&Cb[(NM + m0 + e) * NH + k], Ci[e]);
    }
}

// ---- k_csplit: one-shot C[b][j][k] -> scaled bf16 hi/lo tables [b][k][j].
// Replaces the 32-96x redundant per-block c_prologue in fused/final.
__global__ __launch_bounds__(256) void k_csplit(const float* __restrict__ C,
                                                ushort_t* __restrict__ Chi,
                                                ushort_t* __restrict__ Clo){
    int b = blockIdx.y;
    int t = threadIdx.x;
    int k = blockIdx.x * 64 + (t & 63);
    int j0 = (t >> 6) * 8;
    const float* Cb = C + (long)b * NB * NH;
    uint_t uh[4], ul[4];
    #pragma unroll
    for (int i = 0; i < 4; i++){
        ushort_t h0_, l0_, h1_, l1_;
        {
            int j = j0 + 2 * i;
            float sc = (j == 0) ? (1.0f / S_LEN)
                     : (j < NM) ? (2.0f / S_LEN)
                     : (j == NM) ? 0.f : (-2.0f / S_LEN);
            split_bf(Cb[j * NH + k] * sc, h0_, l0_);
        }
        {
            int j = j0 + 2 * i + 1;
            float sc = (j < NM) ? (2.0f / S_LEN) : (-2.0f / S_LEN);
            split_bf(Cb[j * NH + k] * sc, h1_, l1_);
        }
        uh[i] = (uint_t)h0_ | ((uint_t)h1_ << 16);
        ul[i] = (uint_t)l0_ | ((uint_t)l1_ << 16);
    }
    long o = ((long)b * NH + k) * 32 + j0;
    *(uint4*)(void*)(Chi + o) = (uint4){uh[0], uh[1], uh[2], uh[3]};
    *(uint4*)(void*)(Clo + o) = (uint4){ul[0], ul[1], ul[2], ul[3]};
}

// ---- k_reduce: sum the 32 per-block M partials -> Mfull. Fully coalesced.
__global__ __launch_bounds__(256) void k_reduce(const float* __restrict__ Mpart,
                                                float* __restrict__ Mfull){
    int r = blockIdx.x, b = blockIdx.y;
    int idx = r * 256 + threadIdx.x;
    const float* mp = Mpart + (long)b * 32 * (NB * NH) + idx;
    float acc = 0.f;
    #pragma unroll
    for (int sx = 0; sx < 32; sx++) acc += mp[(long)sx * (NB * NH)];
    Mfull[(long)b * (NB * NH) + idx] = acc;
}

// ---- fused layer (r14 body): ld B-frags from Chi/Clo -> MFMA synth -> gelu ->
//      MFMA DFT -> plain-store per-block M partial.
__global__ __launch_bounds__(256, 4) void k_fused(const ushort_t* __restrict__ Thi,
                                                  const ushort_t* __restrict__ Tlo,
                                                  const ushort_t* __restrict__ TThi,
                                                  const ushort_t* __restrict__ Chi,
                                                  const ushort_t* __restrict__ Clo,
                                                  float* __restrict__ Cnext,
                                                  float* __restrict__ Mpart){
    int b = blockIdx.y;
    int sx = blockIdx.x;
    int s0 = sx * 256;
    int tid = threadIdx.x;
    int w = tid >> 6;
    int lane = tid & 63;
    int c = lane & 15, q = lane >> 4;
    __shared__ __align__(16) ushort_t Glds[NH * GP2];

    bf16x8 Bhi[8], Blo[8];
    #pragma unroll
    for (int kt = 0; kt < 8; kt++){
        long o = ((long)b * NH + kt * 16 + c) * 32 + 8 * q;
        Bhi[kt] = ld8(Chi + o);
        Blo[kt] = ld8(Clo + o);
    }
    if (tid < 32){
        *(float4*)(Cnext + (long)b * NB * NH + sx * 128 + tid * 4)
            = (float4){0.f, 0.f, 0.f, 0.f};
    }
    floatx4 a00 = {0,0,0,0}, a01 = {0,0,0,0}, a10 = {0,0,0,0}, a11 = {0,0,0,0};
    int kt0 = 2 * w;
    for (int p = 0; p < 2; p++){
        int sp = s0 + p * 128;
        #pragma unroll
        for (int sti = 0; sti < 2; sti++){
            int st = w * 2 + sti;
            long ar = (long)(sp + st * 16 + c) * NB + 8 * q;
            bf16x8 Ahi = ld8(Thi + ar);
            bf16x8 Alo = ld8(Tlo + ar);
            #pragma unroll
            for (int kt = 0; kt < 8; kt++){
                floatx4 acc = {0.f, 0.f, 0.f, 0.f};
                acc = MF(Ahi, Bhi[kt], acc);
                acc = MF(Alo, Bhi[kt], acc);
                acc = MF(Ahi, Blo[kt], acc);
                uint_t u0 = (uint_t)f2us(gelu_fast(acc[0])) |
                            ((uint_t)f2us(gelu_fast(acc[1])) << 16);
                uint_t u1 = (uint_t)f2us(gelu_fast(acc[2])) |
                            ((uint_t)f2us(gelu_fast(acc[3])) << 16);
                uint_t* gp = (uint_t*)&Glds[(kt * 16 + c) * GP2 + st * 16 + 4 * q];
                gp[0] = u0; gp[1] = u1;
            }
        }
        __syncthreads();
        #pragma unroll
        for (int kk = 0; kk < 4; kk++){
            long sa = (long)sp + kk * 32 + 8 * q;
            bf16x8 A0h = ld8(TThi + (long)c * S_LEN + sa);
            bf16x8 A1h = ld8(TThi + (long)(16 + c) * S_LEN + sa);
            bf16x8 G0 = ld8(&Glds[(kt0 * 16 + c) * GP2 + kk * 32 + 8 * q]);
            bf16x8 G1 = ld8(&Glds[((kt0 + 1) * 16 + c) * GP2 + kk * 32 + 8 * q]);
            a00 = MF(A0h, G0, a00);
            a01 = MF(A0h, G1, a01);
            a10 = MF(A1h, G0, a10);
            a11 = MF(A1h, G1, a11);
        }
        __syncthreads();
    }
    // block-private partial slice: plain coalesced stores, no atomics
    float* Mb = Mpart + ((long)b * 32 + sx) * (NB * NH);
    #pragma unroll
    for (int r = 0; r < 4; r++){
        Mb[(4 * q + r) * NH + kt0 * 16 + c]            = a00[r];
        Mb[(4 * q + r) * NH + (kt0 + 1) * 16 + c]      = a01[r];
        Mb[(16 + 4 * q + r) * NH + kt0 * 16 + c]       = a10[r];
        Mb[(16 + 4 * q + r) * NH + (kt0 + 1) * 16 + c] = a11[r];
    }
}

// ---- final: ld B-frags from Chi/Clo -> MFMA synth (ILP-grouped) -> out
__global__ __launch_bounds__(256) void k_final(const uint_t* __restrict__ flag,
                                               const ushort_t* __restrict__ Thi,
                                               const ushort_t* __restrict__ Tlo,
                                               const ushort_t* __restrict__ Chi,
                                               const ushort_t* __restrict__ Clo,
                                               const void* __restrict__ ow,
                                               const void* __restrict__ ob,
                                               void* __restrict__ out){
    int tid = threadIdx.x;
    int f32 = (int)flag[0];
    int b = blockIdx.y;
    int s0 = blockIdx.x * 128;
    int w = tid >> 6;
    int lane = tid & 63;
    int c = lane & 15, q = lane >> 4;

    bf16x8 Bhi[8], Blo[8];
    #pragma unroll
    for (int kt = 0; kt < 8; kt++){
        long o = ((long)b * NH + kt * 16 + c) * 32 + 8 * q;
        Bhi[kt] = ld8(Chi + o);
        Blo[kt] = ld8(Clo + o);
    }
    float ow8[8];
    #pragma unroll
    for (int kt = 0; kt < 8; kt++) ow8[kt] = ldf(ow, kt * 16 + c, f32);
    float obv = ldf(ob, 0, f32);
    #pragma unroll
    for (int sti = 0; sti < 2; sti++){
        int st = w * 2 + sti;
        long ar = (long)(s0 + st * 16 + c) * NB + 8 * q;
        bf16x8 Ahi = ld8(Thi + ar);
        bf16x8 Alo = ld8(Tlo + ar);
        float p0 = 0.f, p1 = 0.f, p2 = 0.f, p3 = 0.f;
        #pragma unroll
        for (int g = 0; g < 2; g++){
            int k0 = g * 4;
            floatx4 ac[4];
            #pragma unroll
            for (int t = 0; t < 4; t++) ac[t] = (floatx4){0.f, 0.f, 0.f, 0.f};
            #pragma unroll
            for (int t = 0; t < 4; t++) ac[t] = MF(Ahi, Bhi[k0 + t], ac[t]);
            #pragma unroll
            for (int t = 0; t < 4; t++) ac[t] = MF(Alo, Bhi[k0 + t], ac[t]);
            #pragma unroll
            for (int t = 0; t < 4; t++) ac[t] = MF(Ahi, Blo[k0 + t], ac[t]);
            #pragma unroll
            for (int t = 0; t < 4; t++){
                float o = ow8[k0 + t];
                p0 += gelu_fast(ac[t][0]) * o;
                p1 += gelu_fast(ac[t][1]) * o;
                p2 += gelu_fast(ac[t][2]) * o;
                p3 += gelu_fast(ac[t][3]) * o;
            }
        }
        #pragma unroll
        for (int off = 1; off < 16; off <<= 1){
            p0 += __shfl_xor(p0, off, 16);
            p1 += __shfl_xor(p1, off, 16);
            p2 += __shfl_xor(p2, off, 16);
            p3 += __shfl_xor(p3, off, 16);
        }
        if (c == 0){
            long s = s0 + st * 16 + 4 * q;
            if (f32){
                float4 v = {p0 + obv, p1 + obv, p2 + obv, p3 + obv};
                *(float4*)((float*)out + (long)b * S_LEN + s) = v;
            } else {
                uint_t u0 = (uint_t)f2us(p0 + obv) | ((uint_t)f2us(p1 + obv) << 16);
                uint_t u1 = (uint_t)f2us(p2 + obv) | ((uint_t)f2us(p3 + obv) << 16);
                uint_t* gp = (uint_t*)((ushort_t*)out + (long)b * S_LEN + s);
                gp[0] = u0; gp[1] = u1;
            }
        }
    }
}

extern "C" void kernel_launch(void* const* d_in, const int* in_sizes, int n_in,
                              void* d_out, int out_size, void* d_ws, size_t ws_size,
                              hipStream_t stream) {
    const void* x   = d_in[0];
    const void* pw  = d_in[1];
    const void* pb  = d_in[2];
    const void* wre = d_in[3];
    const void* wim = d_in[4];
    const void* ow  = d_in[5];
    const void* ob  = d_in[6];

    char* ws = (char*)d_ws;
    ushort_t* Thi  = (ushort_t*)(ws);                  // 512 KB
    ushort_t* Tlo  = (ushort_t*)(ws + (512u << 10));   // 512 KB
    ushort_t* TThi = (ushort_t*)(ws + (1024u << 10));  // 512 KB
    float* C0    = (float*)(ws + (1536u << 10));       // 512 KB fp32 C ping
    float* C1    = (float*)(ws + (2048u << 10));       // 512 KB fp32 C pong
    float* Mfull = (float*)(ws + (2560u << 10));       // 512 KB fp32 M [b][j][k]
    uint_t* flag = (uint_t*)(ws + (3072u << 10));      // dtype flag (4 B)
    ushort_t* Chi = (ushort_t*)(ws + (3136u << 10));   // 256 KB bf16 [b][k][j]
    ushort_t* Clo = (ushort_t*)(ws + (3392u << 10));   // 256 KB bf16 [b][k][j]
    float* Mpart = (float*)(ws + (3648u << 10));       // 16 MB fp32 [b][sx][j][k]

    const long wstride = (long)NH * NH * NM;

    k_prep<<<1024, 256, 0, stream>>>(x, pw, pb, Mfull, Thi, Tlo, TThi, C0, flag);
    k_mixA<<<dim3(8, 2, NBATCH), 256, 0, stream>>>(flag, Mfull, wre, wim,
                                                   0 * wstride, C0);
    k_csplit<<<dim3(2, NBATCH), 256, 0, stream>>>(C0, Chi, Clo);
    k_fused<<<dim3(32, NBATCH), 256, 0, stream>>>(Thi, Tlo, TThi, Chi, Clo,
                                                  C1, Mpart);
    k_reduce<<<dim3(16, NBATCH), 256, 0, stream>>>(Mpart, Mfull);
    k_mixA<<<dim3(8, 2, NBATCH), 256, 0, stream>>>(flag, Mfull, wre, wim,
                                                   1 * wstride, C1);
    k_csplit<<<dim3(2, NBATCH), 256, 0, stream>>>(C1, Chi, Clo);
    k_fused<<<dim3(32, NBATCH), 256, 0, stream>>>(Thi, Tlo, TThi, Chi, Clo,
                                                  C0, Mpart);
    k_reduce<<<dim3(16, NBATCH), 256, 0, stream>>>(Mpart, Mfull);
    k_mixA<<<dim3(8, 2, NBATCH), 256, 0, stream>>>(flag, Mfull, wre, wim,
                                                   2 * wstride, C0);
    k_csplit<<<dim3(2, NBATCH), 256, 0, stream>>>(C0, Chi, Clo);
    k_fused<<<dim3(32, NBATCH), 256, 0, stream>>>(Thi, Tlo, TThi, Chi, Clo,
                                                  C1, Mpart);
    k_reduce<<<dim3(16, NBATCH), 256, 0, stream>>>(Mpart, Mfull);
    k_mixA<<<dim3(8, 2, NBATCH), 256, 0, stream>>>(flag, Mfull, wre, wim,
                                                   3 * wstride, C1);
    k_csplit<<<dim3(2, NBATCH), 256, 0, stream>>>(C1, Chi, Clo);
    k_final<<<dim3(64, NBATCH), 256, 0, stream>>>(flag, Thi, Tlo, Chi, Clo,
                                                  ow, ob, d_out);
}